// Round 13
// baseline (108.606 us; speedup 1.0000x reference)
//
#include <hip/hip_runtime.h>
#include <hip/hip_bf16.h>

// SimCLR loss, N=8192, D=128, T=0.1.
//  k1 (prep):  row L2-normalize fp32 -> bf16 znb (unscaled) + znbs (x 10*log2e);
//              selfe[i] = exp2(MFMA-matched self dot); poslog[i] = 10*fp32 dot;
//              + zero partials[64][N] (1 store/thread).
//  k2 (sim):   SYMMETRY-HALVED, 256x256 tiles, upper triangle I<=J (32x32 grid,
//              J<I exits; 528 working blocks ~= 1.03 residency rounds).
//              4 waves x 64 rows (afrag[4][4]); B staged in 2x 32KB chunks
//              (128 B-rows) double-buffered = 64 KB LDS. The 64KB LDS caps
//              occupancy at 2 blocks/CU = 2 waves/SIMD; THEORY UNDER TEST: the
//              VGPR-budget heuristic honors that cap -> budget ~256, demand
//              ~130 fits unspilled (vs R3-R12: small-LDS shapes got 84/64 and
//              spilled everything above).
//              Row-sums -> slot J (plain stores); col-sums -> slot 32+I via
//              fire-and-forget atomicAdd (verified absmax 0.0 in R11/R12).
//              Coverage of tile T: row slots {J>=T}, col slots {32+I, I<T}.
//  k3a/k3b:    denom = sum(64 slots) - selfe; loss = mean(log(denom) - poslog).
//
// Cross-round ledger: R8 full-work 256^2 8-wave = 86.1us total; R11/R12
// half-work 128^2 4-wave = 93.5 -> small tiles lose to per-block overhead
// (8 sequential rounds, 2-iter loop, 2x staging-per-FLOP). This kernel:
// half work AND big tiles AND (predicted) zero spills.
//
// Fixed overhead: ~42 us of every timed window is the harness's 256 MB d_ws
// poison fill draining on the stream (fillBufferAligned @ ~80% HBM peak).

constexpr int N = 8192;
constexpr int D = 128;
constexpr float SCALE = 14.4269504088896341f;  // 10 * log2(e)

typedef short bf16x8 __attribute__((ext_vector_type(8)));
typedef float f32x4 __attribute__((ext_vector_type(4)));

#if __has_builtin(__builtin_amdgcn_exp2f)
#define EXP2(x) __builtin_amdgcn_exp2f(x)
#else
#define EXP2(x) exp2f(x)
#endif

static __device__ __forceinline__ unsigned short f2bf(float x) {
  __hip_bfloat16 h = __float2bfloat16(x);  // RTNE
  unsigned short u;
  __builtin_memcpy(&u, &h, 2);
  return u;
}
static __device__ __forceinline__ float bf2f(unsigned short u) {
  unsigned int x = ((unsigned int)u) << 16;
  float f;
  __builtin_memcpy(&f, &x, 4);
  return f;
}
static __device__ __forceinline__ void gload_lds16(const void* g, void* l) {
  __builtin_amdgcn_global_load_lds(
      (const __attribute__((address_space(1))) unsigned int*)g,
      (__attribute__((address_space(3))) unsigned int*)l, 16, 0, 0);
}

// ------------- kernel 1: normalize + bf16 + self/pos terms + zero partials -------------
__global__ __launch_bounds__(256) void simclr_prep(const float* __restrict__ z,
                                                   unsigned short* __restrict__ znb,
                                                   unsigned short* __restrict__ znbs,
                                                   float* __restrict__ selfe,
                                                   float* __restrict__ poslog,
                                                   float* __restrict__ partials) {
  // zero the 64*N partials (grid 2048*256 = 524288 threads, 1 each)
  const int gid = blockIdx.x * 256 + threadIdx.x;
  partials[gid] = 0.f;

  const int row = blockIdx.x * 4 + (threadIdx.x >> 6);
  const int par = row ^ (N / 2);
  const int lane = threadIdx.x & 63;
  const float2 v = *(const float2*)(z + row * D + lane * 2);
  const float2 b = *(const float2*)(z + par * D + lane * 2);
  float ss = v.x * v.x + v.y * v.y;
  float sb = b.x * b.x + b.y * b.y;
  float dp = v.x * b.x + v.y * b.y;
#pragma unroll
  for (int m = 1; m < 64; m <<= 1) {
    ss += __shfl_xor(ss, m);
    sb += __shfl_xor(sb, m);
    dp += __shfl_xor(dp, m);
  }
  const float rn = rsqrtf(ss);
  const float a0 = v.x * rn, a1 = v.y * rn;
  const unsigned short u0 = f2bf(a0), u1 = f2bf(a1);
  const unsigned short s0 = f2bf(a0 * SCALE), s1 = f2bf(a1 * SCALE);
  *(unsigned int*)(znb + row * D + lane * 2) = (unsigned int)u0 | ((unsigned int)u1 << 16);
  *(unsigned int*)(znbs + row * D + lane * 2) = (unsigned int)s0 | ((unsigned int)s1 << 16);
  // self dot with exactly the MFMA's bf16 products (fp32 sum; order-only mismatch ~1e-5)
  float sa = bf2f(s0) * bf2f(u0) + bf2f(s1) * bf2f(u1);
#pragma unroll
  for (int m = 1; m < 64; m <<= 1) sa += __shfl_xor(sa, m);
  if (lane == 0) {
    selfe[row] = EXP2(sa);
    poslog[row] = 10.0f * dp * rsqrtf(ss * sb);
  }
}

// ---------------- kernel 2: sim, 256x256 upper-triangle tiles, 4 waves, 64KB LDS ----------------
// grid = 32*32 = 1024 blocks (J<I exit); block = 256 threads.
// Wave w owns rows [RB + w*64, +64); B staged in 128-row chunks (32KB), dbuf.
__global__ __launch_bounds__(256)
void simclr_sim(const unsigned short* __restrict__ znb,
                const unsigned short* __restrict__ znbs,
                float* __restrict__ partials) {
  const int bi = blockIdx.x;
  const int I = bi >> 5, J = bi & 31;
  if (J < I) return;  // upper triangle only

  __shared__ unsigned short lb[2][128 * 128];  // 2 x 32KB = 64KB -> 2 blocks/CU cap

  const int RB = I << 8;  // row-tile base (x256)
  const int CB = J << 8;  // col-tile base (x256)
  const int tid = threadIdx.x;
  const int lane = tid & 63;
  const int w = tid >> 6;  // 0..3
  const int l15 = lane & 15, l4 = lane >> 4;
  const bool offdiag = (I != J);

  // A layout (16x16x32): lane holds A[l&15][(l>>4)*8 + 0..7], k = s*32 + l4*8.
  // 4 row-tiles x 4 K-steps = 64 VGPRs (fits only if the 64KB-LDS budget theory holds).
  bf16x8 afrag[4][4];
#pragma unroll
  for (int rt = 0; rt < 4; ++rt)
#pragma unroll
    for (int s = 0; s < 4; ++s)
      afrag[rt][s] =
          *(const bf16x8*)(znbs + (RB + w * 64 + rt * 16 + l15) * D + s * 32 + l4 * 8);

  float dpart[16];
#pragma unroll
  for (int k = 0; k < 16; ++k) dpart[k] = 0.f;

  // Stage chunk cc (128 B-rows = 32KB): 4 waves x 8 instrs, linear LDS dest,
  // inverse-swizzled global source (position sl holds global chunk sl^(rr&7)).
#define STAGE(buf_, cc_)                                                        \
  {                                                                             \
    _Pragma("unroll") for (int i = 0; i < 8; ++i) {                             \
      const int rr = (w * 8 + i) * 4 + l4;                                      \
      const unsigned short* g =                                                 \
          znb + (CB + (cc_) * 128 + rr) * D + ((l15 ^ (rr & 7)) << 3);          \
      gload_lds16(g, (char*)lb[buf_] + (w * 8 + i) * 1024);                     \
    }                                                                           \
  }

  STAGE(0, 0);
  __syncthreads();

  int buf = 0;
#pragma unroll
  for (int cc = 0; cc < 2; ++cc) {
    if (cc < 1) STAGE(buf ^ 1, cc + 1);
    const char* lbc = (const char*)lb[buf];
#pragma unroll
    for (int jt = 0; jt < 8; ++jt) {
      const int jr = jt * 16 + l15;  // B-row within chunk (0..127)
      const int swz = (jr & 7) << 4;
      f32x4 acc[4];
#pragma unroll
      for (int rt = 0; rt < 4; ++rt) acc[rt] = f32x4{0.f, 0.f, 0.f, 0.f};
      // one B fragment live at a time; feeds 4 independent acc chains (ILP).
      // B layout: lane holds B[s*32 + l4*8 + 0..7][l15].
#pragma unroll
      for (int s = 0; s < 4; ++s) {
        const bf16x8 bf = *(const bf16x8*)(lbc + jr * 256 + ((s * 64 + l4 * 16) ^ swz));
#pragma unroll
        for (int rt = 0; rt < 4; ++rt)
          acc[rt] = __builtin_amdgcn_mfma_f32_16x16x32_bf16(afrag[rt][s], bf, acc[rt], 0, 0, 0);
      }
      // acc = 10*log2(e)*dot (A pre-scaled): exp2; row path + col path
      float s8 = 0.f;
#pragma unroll
      for (int rt = 0; rt < 4; ++rt)
#pragma unroll
        for (int r = 0; r < 4; ++r) {
          const float e = EXP2(acc[rt][r]);
          dpart[rt * 4 + r] += e;
          s8 += e;
        }
      if (offdiag) {
        // wave's 64-row column sum: reduce over l4 groups (lane bits 4,5)
        s8 += __shfl_xor(s8, 16);
        s8 += __shfl_xor(s8, 32);
        if (l4 == 0)  // 16 lanes, consecutive cols; 4 waves add to same addr
          atomicAdd(&partials[(32 + I) * N + CB + cc * 128 + jt * 16 + l15], s8);
      }
    }
    __syncthreads();
    buf ^= 1;
  }
#undef STAGE

  // row path: reduce across the 16 column-lanes; slot J of row-tile I
#pragma unroll
  for (int m = 1; m < 16; m <<= 1)
#pragma unroll
    for (int k = 0; k < 16; ++k) dpart[k] += __shfl_xor(dpart[k], m);

  if (l15 == 0) {
    // C/D layout: row = l4*4 + r within each 16-row tile
    float* pp = partials + J * N + RB + w * 64 + l4 * 4;
#pragma unroll
    for (int rt = 0; rt < 4; ++rt)
#pragma unroll
      for (int r = 0; r < 4; ++r) pp[rt * 16 + r] = dpart[rt * 4 + r];
  }
}

// ---------------- kernel 3a: per-row loss, per-block partial sums ----------------
__global__ __launch_bounds__(256) void simclr_rowloss(const float* __restrict__ partials,
                                                      const float* __restrict__ selfe,
                                                      const float* __restrict__ poslog,
                                                      float* __restrict__ bsum) {
  const int tid = threadIdx.x;
  const int i = blockIdx.x * 256 + tid;
  float d = -selfe[i];
#pragma unroll 16
  for (int cb = 0; cb < 64; ++cb) d += partials[cb * N + i];
  float s = logf(d) - poslog[i];
#pragma unroll
  for (int m = 1; m < 64; m <<= 1) s += __shfl_xor(s, m);
  __shared__ float acc[4];
  if ((tid & 63) == 0) acc[tid >> 6] = s;
  __syncthreads();
  if (tid == 0) bsum[blockIdx.x] = acc[0] + acc[1] + acc[2] + acc[3];
}

// ---------------- kernel 3b: final scalar ----------------
__global__ __launch_bounds__(64) void simclr_final(const float* __restrict__ bsum,
                                                   float* __restrict__ out) {
  const int tid = threadIdx.x;
  float s = (tid < 32) ? bsum[tid] : 0.f;
#pragma unroll
  for (int m = 1; m < 64; m <<= 1) s += __shfl_xor(s, m);
  if (tid == 0) out[0] = s * (1.0f / N);
}

extern "C" void kernel_launch(void* const* d_in, const int* in_sizes, int n_in,
                              void* d_out, int out_size, void* d_ws, size_t ws_size,
                              hipStream_t stream) {
  const float* z = (const float*)d_in[0];
  float* out = (float*)d_out;

  float* partials = (float*)d_ws;                      // 64*N (zeroed by prep)
  float* selfe = partials + 64 * N;                    // N
  float* poslog = selfe + N;                           // N
  float* bsum = poslog + N;                            // 32 (pad to 64)
  unsigned short* znb = (unsigned short*)(bsum + 64);  // N*D bf16 (16B-aligned)
  unsigned short* znbs = znb + N * D;                  // N*D bf16

  simclr_prep<<<N / 4, 256, 0, stream>>>(z, znb, znbs, selfe, poslog, partials);
  simclr_sim<<<32 * 32, 256, 0, stream>>>(znb, znbs, partials);
  simclr_rowloss<<<N / 256, 256, 0, stream>>>(partials, selfe, poslog, bsum);
  simclr_final<<<1, 64, 0, stream>>>(bsum, out);
}